// Round 4
// baseline (324.314 us; speedup 1.0000x reference)
//
#include <hip/hip_runtime.h>
#include <math.h>

#define NEMB 200000
#define MM   200
#define KTOP 32
#define BB   1024
#define FEW  5
#define NROW 2058           // 2*BB + 2*FEW (row,half) tasks
#define CH   100            // rows per staged chunk (51.2 KB LDS)

typedef short short8 __attribute__((ext_vector_type(8)));
typedef float floatx4 __attribute__((ext_vector_type(4)));

__device__ __forceinline__ float sigf(float x) { return 1.0f / (1.0f + expf(-x)); }

__device__ __forceinline__ unsigned short f2bf(float x) {   // RNE f32->bf16
    unsigned u = __float_as_uint(x);
    unsigned r = (u + 0x7FFF + ((u >> 16) & 1)) >> 16;
    return (unsigned short)r;
}

// async global->LDS, 16B per lane (1 KB per wave-instruction, no dest VGPRs)
__device__ __forceinline__ void gl_lds16(const float* src, float* ldsdst) {
    __builtin_amdgcn_global_load_lds(
        (const __attribute__((address_space(1))) void*)src,
        (__attribute__((address_space(3))) void*)ldsdst, 16, 0, 0);
}

// ---------------------------------------------------------------------------
// K_front: (a) blocks [0,NROW): per-row fused sims + top-K rank + mean gather.
// Neighbor rows staged to LDS via global_load_lds (13 outstanding 1KB
// transfers per wave — MLP from the vmcnt queue, not VGPRs; fixes the
// 77us latency-bound profile @1.8TB/s). Global src pre-swizzled c^(j&7),
// LDS linear, read applies same XOR (2-way banks). Per-slot math identical
// to round-2/3 (selection-exact, absmax preserved).
// (b) blocks [NROW, NROW+4100): weight conversion fp32->bf16 + LSTM
// gate-compaction remap + bias fold (independent, fills pipeline head).
// NOTE: emb table stays fp32 — bf16 sims perturbs top-K selection.
// ---------------------------------------------------------------------------
__global__ __launch_bounds__(256) void front_kernel(
    const int* __restrict__ query, const int* __restrict__ support,
    const int* __restrict__ qlc, const int* __restrict__ qrc,
    const int* __restrict__ slc, const int* __restrict__ srrc,
    const float* __restrict__ emb, float* __restrict__ avgbuf,
    const float* __restrict__ se_w1, const float* __restrict__ se_w2,
    const float* __restrict__ W_ih, const float* __restrict__ W_hh,
    const float* __restrict__ b_ih, const float* __restrict__ b_hh,
    unsigned short* __restrict__ w1b, unsigned short* __restrict__ w2b,
    unsigned short* __restrict__ wihb, unsigned short* __restrict__ whhb,
    float* __restrict__ bias_c)
{
    if (blockIdx.x >= NROW) {
        int i = (blockIdx.x - NROW) * 256 + threadIdx.x;
        if (i < 131072) { w1b[i] = f2bf(se_w1[i]); return; }
        i -= 131072;
        if (i < 131072) { w2b[i] = f2bf(se_w2[i]); return; }
        i -= 131072;
        if (i < 262144) {       // W_ih compact: row n <- orig ((n>>8)<<9)|(n&255)
            int n = i >> 8, k = i & 255;
            int nb = ((n >> 8) << 9) | (n & 255);
            wihb[i] = f2bf(W_ih[(size_t)nb * 256 + k]); return;
        }
        i -= 262144;
        if (i < 524288) {
            int n = i >> 9, k = i & 511;
            int nb = ((n >> 8) << 9) | (n & 255);
            whhb[i] = f2bf(W_hh[(size_t)nb * 512 + k]); return;
        }
        i -= 524288;
        if (i < 1024) {
            int nb = ((i >> 8) << 9) | (i & 255);
            bias_c[i] = b_ih[nb] + b_hh[nb];
        }
        return;
    }

    __shared__ __align__(16) float rowsL[CH * 128];   // 51200 B staged rows
    __shared__ int   connL[MM * 2];
    __shared__ float simsL[MM];
    __shared__ int   cids[MM];
    __shared__ int   selr[KTOP], sele[KTOP];
    __shared__ float partial[512];
    __shared__ int   nsel;

    const int t   = threadIdx.x;
    const int blk = blockIdx.x;
    const int w    = t >> 6;
    const int lane = t & 63;
    const int quad = lane >> 2, ql = lane & 3;

    const int* conn; int eid;
    if (blk < BB)                { conn = qlc + blk * (MM * 2);                eid = query[blk * 2]; }
    else if (blk < 2 * BB)       { int b = blk - BB;        conn = qrc + b * (MM * 2);  eid = query[b * 2 + 1]; }
    else if (blk < 2 * BB + FEW) { int r = blk - 2 * BB;    conn = slc + r * (MM * 2);  eid = support[r * 2]; }
    else                         { int r = blk - 2 * BB - FEW; conn = srrc + r * (MM * 2); eid = support[r * 2 + 1]; }

    // stage conn -> LDS (one coalesced int4 pass; 400 ints)
    if (t < 100) ((int4*)connL)[t] = ((const int4*)conn)[t];

    // center row (per-lane global loads; latency overlaps conn staging)
    const float4* cb = (const float4*)(emb + (size_t)eid * 128);
    float4 cr[8];
    #pragma unroll
    for (int i = 0; i < 8; ++i) cr[i] = cb[i * 4 + ql];
    float csq = 0.f;
    #pragma unroll
    for (int i = 0; i < 8; ++i)
        csq += cr[i].x * cr[i].x + cr[i].y * cr[i].y + cr[i].z * cr[i].z + cr[i].w * cr[i].w;
    csq += __shfl_xor(csq, 1, 4); csq += __shfl_xor(csq, 2, 4);
    const float cn = sqrtf(csq);

    __syncthreads();   // connL ready

    // two chunks of 100 rows: async-stage then compute sims from LDS
    #pragma unroll 1
    for (int ch = 0; ch < 2; ++ch) {
        const int cbase = ch * CH;
        // stage: 2 rows / instruction, 13 instructions / wave, fire-and-forget
        #pragma unroll
        for (int k = 0; k < 13; ++k) {
            const int g = w * 13 + k;
            if (g < CH / 2) {
                const int j0 = 2 * g;                   // row pair, chunk-rel
                const int jl = cbase + j0 + (lane >> 5);// absolute row (this half-wave)
                const int rid = connL[jl * 2 + 1];
                const float* src = emb + (size_t)rid * 128 + (((lane & 31) ^ (jl & 7)) << 2);
                gl_lds16(src, rowsL + j0 * 128);
            }
        }
        __syncthreads();   // compiler drains vmcnt before barrier

        // sims on staged chunk (identical math/order to round-2)
        #pragma unroll 1
        for (int it = 0; it < 2; ++it) {
            const int jr = it * 64 + w * 16 + quad;     // chunk-rel row
            if (jr < CH) {
                const int j  = cbase + jr;
                const int sw = j & 7;
                float4 E[8];
                #pragma unroll
                for (int i = 0; i < 8; ++i)
                    E[i] = *(const float4*)&rowsL[jr * 128 + (((i * 4 + ql) ^ sw) << 2)];
                float num = 0.f, sq = 0.f;
                #pragma unroll
                for (int i = 0; i < 8; ++i) {
                    num += cr[i].x * E[i].x + cr[i].y * E[i].y + cr[i].z * E[i].z + cr[i].w * E[i].w;
                    sq  += E[i].x * E[i].x + E[i].y * E[i].y + E[i].z * E[i].z + E[i].w * E[i].w;
                }
                num += __shfl_xor(num, 1, 4); num += __shfl_xor(num, 2, 4);
                sq  += __shfl_xor(sq , 1, 4); sq  += __shfl_xor(sq , 2, 4);
                if (ql == 0) simsL[j] = num / fmaxf(cn * sqrtf(sq), 1e-8f);
            }
        }
        __syncthreads();   // all reads done before next chunk overwrites rowsL
    }

    if (t < MM) cids[t] = connL[t * 2 + 1];
    if (t == 0) nsel = 0;
    __syncthreads();

    // rank: top-K with tie-break lower index (float4 scan over LDS sims)
    if (t < MM) {
        float st = simsL[t];
        int cnt = 0;
        #pragma unroll 2
        for (int j4 = 0; j4 < MM / 4; ++j4) {
            float4 s4 = *(const float4*)&simsL[j4 * 4];
            int jb = j4 * 4;
            cnt += (s4.x > st) || (s4.x == st && (jb + 0) < t);
            cnt += (s4.y > st) || (s4.y == st && (jb + 1) < t);
            cnt += (s4.z > st) || (s4.z == st && (jb + 2) < t);
            cnt += (s4.w > st) || (s4.w == st && (jb + 3) < t);
        }
        if (cnt < KTOP) {
            int p = atomicAdd(&nsel, 1);
            selr[p] = connL[t * 2 + 0];
            sele[p] = cids[t];
        }
    }
    __syncthreads();

    // mean gather of selected rel/ent rows -> avgbuf[blk] (ent rows L2-hot)
    {
        const int slot = t & 127;
        const int hpar = t >> 7;
        const bool isEnt = slot >= 64;
        float2 acc = make_float2(0.f, 0.f);
        for (int s = hpar; s < KTOP; s += 2) {
            int rid = isEnt ? sele[s] : selr[s];
            float2 v = ((const float2*)(emb + (size_t)rid * 128))[slot & 63];
            acc.x += v.x; acc.y += v.y;
        }
        ((float2*)partial)[t] = acc;
    }
    __syncthreads();
    if (t < 128) {
        float2 a = ((float2*)partial)[t];
        float2 b = ((float2*)partial)[t + 128];
        ((float2*)(avgbuf + (size_t)blk * 256))[t] =
            make_float2((a.x + b.x) * (1.0f / KTOP), (a.y + b.y) * (1.0f / KTOP));
    }
}

// ---------------------------------------------------------------------------
// K3: GCN matvec as fp32 GEMM -> qn2 (fp32) + qn2_bf (bf16)
// ---------------------------------------------------------------------------
__global__ __launch_bounds__(256) void gcn_gemm_kernel(
    const float* __restrict__ A, const float* __restrict__ W,
    const float* __restrict__ gcn_bias, const float* __restrict__ gcn_b,
    float* __restrict__ qn2, unsigned short* __restrict__ qn2b)
{
    __shared__ float As[16][68];
    __shared__ float Ws[16][68];
    const int t  = threadIdx.x;
    const int bm = blockIdx.y * 64, bn = blockIdx.x * 64;
    const int tx = t & 15, ty = t >> 4;
    const int lrow = t >> 2, lk4 = (t & 3) * 4;

    const float* Ap = A + (size_t)(bm + lrow) * 256 + lk4;
    const float* Wp = W + (size_t)(bn + lrow) * 256 + lk4;

    float acc[4][4] = {};
    for (int k0 = 0; k0 < 256; k0 += 16) {
        float4 av = *(const float4*)(Ap + k0);
        float4 wv = *(const float4*)(Wp + k0);
        __syncthreads();
        As[lk4 + 0][lrow] = av.x; As[lk4 + 1][lrow] = av.y;
        As[lk4 + 2][lrow] = av.z; As[lk4 + 3][lrow] = av.w;
        Ws[lk4 + 0][lrow] = wv.x; Ws[lk4 + 1][lrow] = wv.y;
        Ws[lk4 + 2][lrow] = wv.z; Ws[lk4 + 3][lrow] = wv.w;
        __syncthreads();
        #pragma unroll
        for (int kk = 0; kk < 16; ++kk) {
            float4 a = *(const float4*)&As[kk][ty * 4];
            float4 b = *(const float4*)&Ws[kk][tx * 4];
            acc[0][0] += a.x * b.x; acc[0][1] += a.x * b.y; acc[0][2] += a.x * b.z; acc[0][3] += a.x * b.w;
            acc[1][0] += a.y * b.x; acc[1][1] += a.y * b.y; acc[1][2] += a.y * b.z; acc[1][3] += a.y * b.w;
            acc[2][0] += a.z * b.x; acc[2][1] += a.z * b.y; acc[2][2] += a.z * b.z; acc[2][3] += a.z * b.w;
            acc[3][0] += a.w * b.x; acc[3][1] += a.w * b.y; acc[3][2] += a.w * b.z; acc[3][3] += a.w * b.w;
        }
    }

    const int n0 = bn + tx * 4;
    float4 bv = *(const float4*)(gcn_bias + n0);
    float4 b2 = *(const float4*)(gcn_b + n0);
    bv.x += b2.x; bv.y += b2.y; bv.z += b2.z; bv.w += b2.w;

    #pragma unroll
    for (int i = 0; i < 4; ++i) {
        int tk = bm + ty * 4 + i;
        if (tk >= NROW) continue;
        int row_out, half;
        if (tk < BB)                { row_out = tk;                 half = 0; }
        else if (tk < 2 * BB)       { row_out = tk - BB;            half = 1; }
        else if (tk < 2 * BB + FEW) { row_out = BB + tk - 2 * BB;   half = 0; }
        else                        { row_out = BB + tk - 2 * BB - FEW; half = 1; }
        float4 v = make_float4(tanhf(acc[i][0] + bv.x), tanhf(acc[i][1] + bv.y),
                               tanhf(acc[i][2] + bv.z), tanhf(acc[i][3] + bv.w));
        size_t base = (size_t)row_out * 256 + half * 128 + n0;
        *(float4*)(qn2 + base) = v;
        ushort4 u = make_ushort4(f2bf(v.x), f2bf(v.y), f2bf(v.z), f2bf(v.w));
        *(ushort4*)(qn2b + base) = u;
    }
}

// ---------------------------------------------------------------------------
// MFMA bf16 GEMM: C[M,N](fp32 or relu->bf16) = A_bf[M,K] @ W_bf[N,K]^T
// (+bias fp32)(+add fp32). 64x64 block tile, 4 waves, 16x16x32 mfma.
// ---------------------------------------------------------------------------
template <bool RELU_BF_OUT, bool HAS_ADD, bool HAS_BIAS>
__global__ __launch_bounds__(256) void mfma_gemm(
    const unsigned short* __restrict__ Abf, const unsigned short* __restrict__ Wbf,
    const float* __restrict__ bias, const float* __restrict__ add,
    float* __restrict__ Cf, unsigned short* __restrict__ Cbf,
    int N_, int K_)
{
    __shared__ short Asl[64][40];   // +8 pad: 2-way LDS conflicts only (free)
    __shared__ short Wsl[64][40];
    const int t = threadIdx.x;
    const int w = t >> 6, l = t & 63;
    const int l15 = l & 15, q = l >> 4;
    const int bm = blockIdx.y * 64, bn = blockIdx.x * 64;

    const int srow = t >> 2, skoff = (t & 3) * 8;
    const unsigned short* Ap = Abf + (size_t)(bm + srow) * K_ + skoff;
    const unsigned short* Wp = Wbf + (size_t)(bn + srow) * K_ + skoff;

    floatx4 acc[4];
    #pragma unroll
    for (int jf = 0; jf < 4; ++jf) acc[jf] = (floatx4){0.f, 0.f, 0.f, 0.f};

    for (int k0 = 0; k0 < K_; k0 += 32) {
        short8 av = *(const short8*)(Ap + k0);
        short8 wv = *(const short8*)(Wp + k0);
        __syncthreads();
        *(short8*)&Asl[srow][skoff] = av;
        *(short8*)&Wsl[srow][skoff] = wv;
        __syncthreads();
        short8 a = *(const short8*)&Asl[w * 16 + l15][q * 8];
        #pragma unroll
        for (int jf = 0; jf < 4; ++jf) {
            short8 b = *(const short8*)&Wsl[jf * 16 + l15][q * 8];
            acc[jf] = __builtin_amdgcn_mfma_f32_16x16x32_bf16(a, b, acc[jf], 0, 0, 0);
        }
    }

    #pragma unroll
    for (int jf = 0; jf < 4; ++jf) {
        const int col = bn + jf * 16 + l15;
        float bv = HAS_BIAS ? bias[col] : 0.f;
        #pragma unroll
        for (int r = 0; r < 4; ++r) {
            const int m = bm + w * 16 + q * 4 + r;
            float v = acc[jf][r] + bv;
            if (HAS_ADD) v += add[(size_t)m * N_ + col];
            if (RELU_BF_OUT) Cbf[(size_t)m * N_ + col] = f2bf(fmaxf(v, 0.f));
            else             Cf [(size_t)m * N_ + col] = v;
        }
    }
}

// ---------------------------------------------------------------------------
// LayerNorm per row (+ qg2_bf write); block 1024: support rows + mean + l2norm
// ---------------------------------------------------------------------------
__global__ __launch_bounds__(256) void ln_kernel(
    const float* __restrict__ y, const float* __restrict__ g,
    const float* __restrict__ beta, float* __restrict__ out,
    unsigned short* __restrict__ outb, float* __restrict__ sg0,
    float* __restrict__ sgn)
{
    __shared__ float rs[4], rq[4];
    const int t = threadIdx.x;
    const int lane = t & 63, wave = t >> 6;

    if (blockIdx.x < 1024) {
        const int row = blockIdx.x;
        float v = y[row * 256 + t];
        float s = v, q = v * v;
        #pragma unroll
        for (int i = 32; i >= 1; i >>= 1) { s += __shfl_xor(s, i, 64); q += __shfl_xor(q, i, 64); }
        if (lane == 0) { rs[wave] = s; rq[wave] = q; }
        __syncthreads();
        float tot  = rs[0] + rs[1] + rs[2] + rs[3];
        float totq = rq[0] + rq[1] + rq[2] + rq[3];
        float mu  = tot * (1.0f / 256.0f);
        float var = fmaxf(totq * (1.0f / 256.0f) - mu * mu, 0.0f);
        float o = g[t] * (v - mu) / sqrtf(var + 1e-5f) + beta[t];
        out[row * 256 + t]  = o;
        outb[row * 256 + t] = f2bf(o);
    } else {
        float acc = 0.f;
        for (int r = 0; r < FEW; ++r) {
            __syncthreads();
            float v = y[(BB + r) * 256 + t];
            float s = v, q = v * v;
            #pragma unroll
            for (int i = 32; i >= 1; i >>= 1) { s += __shfl_xor(s, i, 64); q += __shfl_xor(q, i, 64); }
            if (lane == 0) { rs[wave] = s; rq[wave] = q; }
            __syncthreads();
            float tot  = rs[0] + rs[1] + rs[2] + rs[3];
            float totq = rq[0] + rq[1] + rq[2] + rq[3];
            float mu  = tot * (1.0f / 256.0f);
            float var = fmaxf(totq * (1.0f / 256.0f) - mu * mu, 0.0f);
            acc += g[t] * (v - mu) / sqrtf(var + 1e-5f) + beta[t];
        }
        acc *= (1.0f / FEW);
        sg0[t] = acc;
        __syncthreads();
        float q = acc * acc;
        #pragma unroll
        for (int i = 32; i >= 1; i >>= 1) q += __shfl_xor(q, i, 64);
        if (lane == 0) rq[wave] = q;
        __syncthreads();
        float nrm = sqrtf(rq[0] + rq[1] + rq[2] + rq[3]);
        sgn[t] = acc / fmaxf(nrm, 1e-12f);
    }
}

// gates compact layout: [0:256)=i [256:512)=f [512:768)=g [768:1024)=o
__global__ __launch_bounds__(256) void lstm_step1_kernel(
    const float* __restrict__ gates, const float* __restrict__ qg,
    const float* __restrict__ sg0, float* __restrict__ c1,
    unsigned short* __restrict__ hrb)
{
    const int row = blockIdx.x, t = threadIdx.x;
    const float* gr = gates + row * 1024;
    float iv = gr[t], gv = gr[512 + t], ov = gr[768 + t];
    float cv = sigf(iv) * tanhf(gv);          // c0 = 0 => f-term drops
    c1[row * 256 + t] = cv;
    float hf = sigf(ov) * tanhf(cv);
    hrb[row * 512 + t]       = f2bf(qg[row * 256 + t] + hf);  // h1
    hrb[row * 512 + 256 + t] = f2bf(sg0[t]);                  // r (attn == 1)
}

__global__ __launch_bounds__(256) void lstm_step2_kernel(
    const float* __restrict__ gates, const float* __restrict__ c1,
    const float* __restrict__ qg, const float* __restrict__ sgn,
    float* __restrict__ outv)
{
    __shared__ float rn[4], rd[4];
    const int row = blockIdx.x, t = threadIdx.x;
    const int lane = t & 63, wave = t >> 6;
    const float* gr = gates + row * 1024;
    float iv = gr[t], fv = gr[256 + t], gv = gr[512 + t], ov = gr[768 + t];
    float cv = sigf(fv) * c1[row * 256 + t] + sigf(iv) * tanhf(gv);
    float h2 = qg[row * 256 + t] + sigf(ov) * tanhf(cv);
    float nn = h2 * h2, dd = h2 * sgn[t];
    #pragma unroll
    for (int i = 32; i >= 1; i >>= 1) { nn += __shfl_xor(nn, i, 64); dd += __shfl_xor(dd, i, 64); }
    if (lane == 0) { rn[wave] = nn; rd[wave] = dd; }
    __syncthreads();
    if (t == 0) {
        float n2 = rn[0] + rn[1] + rn[2] + rn[3];
        float dt = rd[0] + rd[1] + rd[2] + rd[3];
        outv[row] = dt / fmaxf(sqrtf(n2), 1e-12f);
    }
}

extern "C" void kernel_launch(void* const* d_in, const int* in_sizes, int n_in,
                              void* d_out, int out_size, void* d_ws, size_t ws_size,
                              hipStream_t stream)
{
    const int*   query    = (const int*)d_in[0];
    const int*   support  = (const int*)d_in[1];
    const int*   q_l_conn = (const int*)d_in[2];
    const int*   q_r_conn = (const int*)d_in[4];
    const int*   s_l_conn = (const int*)d_in[6];
    const int*   s_r_conn = (const int*)d_in[8];
    const float* emb      = (const float*)d_in[10];
    const float* gcn_W    = (const float*)d_in[11];
    const float* gcn_bias = (const float*)d_in[12];
    const float* gcn_b    = (const float*)d_in[13];
    const float* se_w1    = (const float*)d_in[14];
    const float* se_b1    = (const float*)d_in[15];
    const float* se_w2    = (const float*)d_in[16];
    const float* se_b2    = (const float*)d_in[17];
    const float* ln_g     = (const float*)d_in[18];
    const float* ln_b     = (const float*)d_in[19];
    const float* W_ih     = (const float*)d_in[20];
    const float* W_hh     = (const float*)d_in[21];
    const float* b_ih     = (const float*)d_in[22];
    const float* b_hh     = (const float*)d_in[23];
    float* out = (float*)d_out;

    float* ws     = (float*)d_ws;
    float* qn2    = ws;                    // 1088*256 f
    float* yq     = qn2    + 1088 * 256;   // 1088*256 f
    float* qg2    = yq     + 1088 * 256;   // 1088*256 f
    float* sg0    = qg2    + 1088 * 256;   // 256
    float* sgn    = sg0    + 256;          // 256
    float* gates  = sgn    + 256;          // 1024*1024 f
    float* c1     = gates  + 1024 * 1024;  // 1024*256 f
    float* avgbuf = c1     + 1024 * 256;   // 2112*256 f
    float* bias_c = avgbuf + 2112 * 256;   // 1024 f
    unsigned short* qn2b = (unsigned short*)(bias_c + 1024);  // 1088*256 sh
    unsigned short* h1b  = qn2b + 1088 * 256;                 // 1088*512 sh
    unsigned short* qg2b = h1b  + 1088 * 512;                 // 1024*256 sh
    unsigned short* hrb  = qg2b + 1024 * 256;                 // 1024*512 sh
    unsigned short* w1b  = hrb  + 1024 * 512;                 // 512*256 sh
    unsigned short* w2b  = w1b  + 512 * 256;                  // 256*512 sh
    unsigned short* wihb = w2b  + 256 * 512;                  // 1024*256 sh
    unsigned short* whhb = wihb + 1024 * 256;                 // 1024*512 sh

    // 1. front: per-row sims+rank+avg -> avgbuf  ||  weight convert
    front_kernel<<<NROW + 4100, 256, 0, stream>>>(
        query, support, q_l_conn, q_r_conn, s_l_conn, s_r_conn, emb, avgbuf,
        se_w1, se_w2, W_ih, W_hh, b_ih, b_hh, w1b, w2b, wihb, whhb, bias_c);

    // 2. GCN matvec GEMM -> qn2 (f32 + bf16)
    gcn_gemm_kernel<<<dim3(2, 33), 256, 0, stream>>>(
        avgbuf, gcn_W, gcn_bias, gcn_b, qn2, qn2b);

    // 3. SE GEMM1 (MFMA): h1_bf = bf16(relu(qn2 @ w1^T + b1))
    mfma_gemm<true, false, true><<<dim3(8, 17), 256, 0, stream>>>(
        qn2b, w1b, se_b1, nullptr, nullptr, h1b, 512, 256);

    // 4. SE GEMM2 (MFMA): yq = h1 @ w2^T + b2 + qn2
    mfma_gemm<false, true, true><<<dim3(4, 17), 256, 0, stream>>>(
        h1b, w2b, se_b2, qn2, yq, nullptr, 256, 512);

    // 5. LayerNorm -> qg2 (f32 + bf16) (+ support mean + l2norm in block 1024)
    ln_kernel<<<1025, 256, 0, stream>>>(yq, ln_g, ln_b, qg2, qg2b, sg0, sgn);

    // 6. gates = qg2 @ W_ih'^T + (b_ih+b_hh)  (MFMA, gate-compacted)
    mfma_gemm<false, false, true><<<dim3(16, 16), 256, 0, stream>>>(
        qg2b, wihb, bias_c, nullptr, gates, nullptr, 1024, 256);

    // 7. LSTM step 1 (c0=0, h_r0=0) -> c1, hr_bf
    lstm_step1_kernel<<<1024, 256, 0, stream>>>(gates, qg2, sg0, c1, hrb);

    // 8. gates += hr @ W_hh'^T  (MFMA, in-place add)
    mfma_gemm<false, true, false><<<dim3(16, 16), 256, 0, stream>>>(
        hrb, whhb, nullptr, gates, gates, nullptr, 1024, 512);

    // 9. LSTM step 2 + l2norm + dot(support_gn)
    lstm_step2_kernel<<<1024, 256, 0, stream>>>(gates, c1, qg2, sgn, out);
}

// Round 5
// 292.683 us; speedup vs baseline: 1.1081x; 1.1081x over previous
//
#include <hip/hip_runtime.h>
#include <math.h>

#define NEMB 200000
#define MM   200
#define KTOP 32
#define BB   1024
#define FEW  5
#define NROW 2058           // 2*BB + 2*FEW (row,half) tasks

typedef short short8 __attribute__((ext_vector_type(8)));
typedef float floatx4 __attribute__((ext_vector_type(4)));

__device__ __forceinline__ float sigf(float x) { return 1.0f / (1.0f + expf(-x)); }

__device__ __forceinline__ unsigned short f2bf(float x) {   // RNE f32->bf16
    unsigned u = __float_as_uint(x);
    unsigned r = (u + 0x7FFF + ((u >> 16) & 1)) >> 16;
    return (unsigned short)r;
}

// force-issue 16B global loads back-to-back (MLP pinned by volatile asm order,
// not by the compiler's VGPR-minimizing scheduler — R3's VGPR=40 showed it
// serializes source-level load batches down to ~4 in flight)
#define GLD(dst, ptr)       asm volatile("global_load_dwordx4 %0, %1, off"              : "=v"(dst) : "v"(ptr))
#define GLDO(dst, ptr, off) asm volatile("global_load_dwordx4 %0, %1, off offset:" #off : "=v"(dst) : "v"(ptr))

// ---------------------------------------------------------------------------
// K_front: (a) blocks [0,NROW): per-row fused sims + top-K rank + mean gather
// -> avgbuf. 4 waves/block, barrier-free sims loop (R2 structure, 75us) but
// with 16 asm-issued row loads in flight per quad-pair (~16KB/wave) and one
// vmcnt(0)+sched_barrier before consumption. Per-slot math identical to
// round-2 (selection-exact, absmax preserved).
// (b) blocks [NROW, NROW+4100): weight conversion fp32->bf16 + LSTM
// gate-compaction remap + bias fold (independent, fills pipeline head).
// NOTE: emb table stays fp32 — bf16 sims perturbs top-K selection.
// ---------------------------------------------------------------------------
__global__ __launch_bounds__(256) void front_kernel(
    const int* __restrict__ query, const int* __restrict__ support,
    const int* __restrict__ qlc, const int* __restrict__ qrc,
    const int* __restrict__ slc, const int* __restrict__ srrc,
    const float* __restrict__ emb, float* __restrict__ avgbuf,
    const float* __restrict__ se_w1, const float* __restrict__ se_w2,
    const float* __restrict__ W_ih, const float* __restrict__ W_hh,
    const float* __restrict__ b_ih, const float* __restrict__ b_hh,
    unsigned short* __restrict__ w1b, unsigned short* __restrict__ w2b,
    unsigned short* __restrict__ wihb, unsigned short* __restrict__ whhb,
    float* __restrict__ bias_c)
{
    if (blockIdx.x >= NROW) {
        int i = (blockIdx.x - NROW) * 256 + threadIdx.x;
        if (i < 131072) { w1b[i] = f2bf(se_w1[i]); return; }
        i -= 131072;
        if (i < 131072) { w2b[i] = f2bf(se_w2[i]); return; }
        i -= 131072;
        if (i < 262144) {       // W_ih compact: row n <- orig ((n>>8)<<9)|(n&255)
            int n = i >> 8, k = i & 255;
            int nb = ((n >> 8) << 9) | (n & 255);
            wihb[i] = f2bf(W_ih[(size_t)nb * 256 + k]); return;
        }
        i -= 262144;
        if (i < 524288) {
            int n = i >> 9, k = i & 511;
            int nb = ((n >> 8) << 9) | (n & 255);
            whhb[i] = f2bf(W_hh[(size_t)nb * 512 + k]); return;
        }
        i -= 524288;
        if (i < 1024) {
            int nb = ((i >> 8) << 9) | (i & 255);
            bias_c[i] = b_ih[nb] + b_hh[nb];
        }
        return;
    }

    __shared__ int   connL[MM * 2];
    __shared__ float simsL[MM];
    __shared__ int   cids[MM];
    __shared__ int   selr[KTOP], sele[KTOP];
    __shared__ float partial[512];
    __shared__ int   nsel;

    const int t   = threadIdx.x;
    const int blk = blockIdx.x;
    const int w    = t >> 6;
    const int lane = t & 63;
    const int quad = lane >> 2, ql = lane & 3;

    const int* conn; int eid;
    if (blk < BB)                { conn = qlc + blk * (MM * 2);                eid = query[blk * 2]; }
    else if (blk < 2 * BB)       { int b = blk - BB;        conn = qrc + b * (MM * 2);  eid = query[b * 2 + 1]; }
    else if (blk < 2 * BB + FEW) { int r = blk - 2 * BB;    conn = slc + r * (MM * 2);  eid = support[r * 2]; }
    else                         { int r = blk - 2 * BB - FEW; conn = srrc + r * (MM * 2); eid = support[r * 2 + 1]; }

    // stage conn -> LDS (one coalesced int4 pass; 400 ints)
    if (t < 100) ((int4*)connL)[t] = ((const int4*)conn)[t];

    // center row (per-lane loads; latency overlaps conn staging)
    const float4* cb = (const float4*)(emb + (size_t)eid * 128);
    float4 cr[8];
    #pragma unroll
    for (int i = 0; i < 8; ++i) cr[i] = cb[i * 4 + ql];
    float csq = 0.f;
    #pragma unroll
    for (int i = 0; i < 8; ++i)
        csq += cr[i].x * cr[i].x + cr[i].y * cr[i].y + cr[i].z * cr[i].z + cr[i].w * cr[i].w;
    csq += __shfl_xor(csq, 1, 4); csq += __shfl_xor(csq, 2, 4);
    const float cn = sqrtf(csq);

    __syncthreads();   // connL ready

    // sims: 2 passes, 2 rows per quad per pass, 16 asm loads in flight
    #pragma unroll 1
    for (int p = 0; p < 2; ++p) {
        const int ja = p * 64 + w * 16 + quad;          // [0,128) always valid
        const int jb = ja + 128;                        // [128,256)
        const bool vb = jb < MM;
        const int  ra = connL[ja * 2 + 1];
        const int  rb = vb ? connL[jb * 2 + 1] : 0;
        const float* pa = emb + (size_t)ra * 128 + ql * 4;
        const float* pb = emb + (size_t)rb * 128 + ql * 4;

        floatx4 Ea[8], Eb[8];
        GLD (Ea[0], pa);
        GLDO(Ea[1], pa, 64);
        GLDO(Ea[2], pa, 128);
        GLDO(Ea[3], pa, 192);
        GLDO(Ea[4], pa, 256);
        GLDO(Ea[5], pa, 320);
        GLDO(Ea[6], pa, 384);
        GLDO(Ea[7], pa, 448);
        if (vb) {
            GLD (Eb[0], pb);
            GLDO(Eb[1], pb, 64);
            GLDO(Eb[2], pb, 128);
            GLDO(Eb[3], pb, 192);
            GLDO(Eb[4], pb, 256);
            GLDO(Eb[5], pb, 320);
            GLDO(Eb[6], pb, 384);
            GLDO(Eb[7], pb, 448);
        }
        asm volatile("s_waitcnt vmcnt(0)" ::: "memory");
        __builtin_amdgcn_sched_barrier(0);   // rule #18: pin consumption after wait

        float numa = 0.f, sqa = 0.f;
        #pragma unroll
        for (int i = 0; i < 8; ++i) {
            numa += cr[i].x * Ea[i][0] + cr[i].y * Ea[i][1] + cr[i].z * Ea[i][2] + cr[i].w * Ea[i][3];
            sqa  += Ea[i][0] * Ea[i][0] + Ea[i][1] * Ea[i][1] + Ea[i][2] * Ea[i][2] + Ea[i][3] * Ea[i][3];
        }
        float numb = 0.f, sqb = 0.f;
        if (vb) {
            #pragma unroll
            for (int i = 0; i < 8; ++i) {
                numb += cr[i].x * Eb[i][0] + cr[i].y * Eb[i][1] + cr[i].z * Eb[i][2] + cr[i].w * Eb[i][3];
                sqb  += Eb[i][0] * Eb[i][0] + Eb[i][1] * Eb[i][1] + Eb[i][2] * Eb[i][2] + Eb[i][3] * Eb[i][3];
            }
        }
        numa += __shfl_xor(numa, 1, 4); numa += __shfl_xor(numa, 2, 4);
        sqa  += __shfl_xor(sqa , 1, 4); sqa  += __shfl_xor(sqa , 2, 4);
        numb += __shfl_xor(numb, 1, 4); numb += __shfl_xor(numb, 2, 4);
        sqb  += __shfl_xor(sqb , 1, 4); sqb  += __shfl_xor(sqb , 2, 4);
        if (ql == 0) {
            simsL[ja] = numa / fmaxf(cn * sqrtf(sqa), 1e-8f);
            if (vb) simsL[jb] = numb / fmaxf(cn * sqrtf(sqb), 1e-8f);
        }
    }
    if (t < MM) cids[t] = connL[t * 2 + 1];
    if (t == 0) nsel = 0;
    __syncthreads();

    // rank: top-K with tie-break lower index (float4 scan over LDS sims)
    if (t < MM) {
        float st = simsL[t];
        int cnt = 0;
        #pragma unroll 2
        for (int j4 = 0; j4 < MM / 4; ++j4) {
            float4 s4 = *(const float4*)&simsL[j4 * 4];
            int jb = j4 * 4;
            cnt += (s4.x > st) || (s4.x == st && (jb + 0) < t);
            cnt += (s4.y > st) || (s4.y == st && (jb + 1) < t);
            cnt += (s4.z > st) || (s4.z == st && (jb + 2) < t);
            cnt += (s4.w > st) || (s4.w == st && (jb + 3) < t);
        }
        if (cnt < KTOP) {
            int p = atomicAdd(&nsel, 1);
            selr[p] = connL[t * 2 + 0];
            sele[p] = cids[t];
        }
    }
    __syncthreads();

    // mean gather of selected rel/ent rows -> avgbuf[blk] (ent rows L2-hot)
    {
        const int slot = t & 127;
        const int hpar = t >> 7;
        const bool isEnt = slot >= 64;
        float2 acc = make_float2(0.f, 0.f);
        for (int s = hpar; s < KTOP; s += 2) {
            int rid = isEnt ? sele[s] : selr[s];
            float2 v = ((const float2*)(emb + (size_t)rid * 128))[slot & 63];
            acc.x += v.x; acc.y += v.y;
        }
        ((float2*)partial)[t] = acc;
    }
    __syncthreads();
    if (t < 128) {
        float2 a = ((float2*)partial)[t];
        float2 b = ((float2*)partial)[t + 128];
        ((float2*)(avgbuf + (size_t)blk * 256))[t] =
            make_float2((a.x + b.x) * (1.0f / KTOP), (a.y + b.y) * (1.0f / KTOP));
    }
}

// ---------------------------------------------------------------------------
// K3: GCN matvec as fp32 GEMM -> qn2 (fp32) + qn2_bf (bf16)
// ---------------------------------------------------------------------------
__global__ __launch_bounds__(256) void gcn_gemm_kernel(
    const float* __restrict__ A, const float* __restrict__ W,
    const float* __restrict__ gcn_bias, const float* __restrict__ gcn_b,
    float* __restrict__ qn2, unsigned short* __restrict__ qn2b)
{
    __shared__ float As[16][68];
    __shared__ float Ws[16][68];
    const int t  = threadIdx.x;
    const int bm = blockIdx.y * 64, bn = blockIdx.x * 64;
    const int tx = t & 15, ty = t >> 4;
    const int lrow = t >> 2, lk4 = (t & 3) * 4;

    const float* Ap = A + (size_t)(bm + lrow) * 256 + lk4;
    const float* Wp = W + (size_t)(bn + lrow) * 256 + lk4;

    float acc[4][4] = {};
    for (int k0 = 0; k0 < 256; k0 += 16) {
        float4 av = *(const float4*)(Ap + k0);
        float4 wv = *(const float4*)(Wp + k0);
        __syncthreads();
        As[lk4 + 0][lrow] = av.x; As[lk4 + 1][lrow] = av.y;
        As[lk4 + 2][lrow] = av.z; As[lk4 + 3][lrow] = av.w;
        Ws[lk4 + 0][lrow] = wv.x; Ws[lk4 + 1][lrow] = wv.y;
        Ws[lk4 + 2][lrow] = wv.z; Ws[lk4 + 3][lrow] = wv.w;
        __syncthreads();
        #pragma unroll
        for (int kk = 0; kk < 16; ++kk) {
            float4 a = *(const float4*)&As[kk][ty * 4];
            float4 b = *(const float4*)&Ws[kk][tx * 4];
            acc[0][0] += a.x * b.x; acc[0][1] += a.x * b.y; acc[0][2] += a.x * b.z; acc[0][3] += a.x * b.w;
            acc[1][0] += a.y * b.x; acc[1][1] += a.y * b.y; acc[1][2] += a.y * b.z; acc[1][3] += a.y * b.w;
            acc[2][0] += a.z * b.x; acc[2][1] += a.z * b.y; acc[2][2] += a.z * b.z; acc[2][3] += a.z * b.w;
            acc[3][0] += a.w * b.x; acc[3][1] += a.w * b.y; acc[3][2] += a.w * b.z; acc[3][3] += a.w * b.w;
        }
    }

    const int n0 = bn + tx * 4;
    float4 bv = *(const float4*)(gcn_bias + n0);
    float4 b2 = *(const float4*)(gcn_b + n0);
    bv.x += b2.x; bv.y += b2.y; bv.z += b2.z; bv.w += b2.w;

    #pragma unroll
    for (int i = 0; i < 4; ++i) {
        int tk = bm + ty * 4 + i;
        if (tk >= NROW) continue;
        int row_out, half;
        if (tk < BB)                { row_out = tk;                 half = 0; }
        else if (tk < 2 * BB)       { row_out = tk - BB;            half = 1; }
        else if (tk < 2 * BB + FEW) { row_out = BB + tk - 2 * BB;   half = 0; }
        else                        { row_out = BB + tk - 2 * BB - FEW; half = 1; }
        float4 v = make_float4(tanhf(acc[i][0] + bv.x), tanhf(acc[i][1] + bv.y),
                               tanhf(acc[i][2] + bv.z), tanhf(acc[i][3] + bv.w));
        size_t base = (size_t)row_out * 256 + half * 128 + n0;
        *(float4*)(qn2 + base) = v;
        ushort4 u = make_ushort4(f2bf(v.x), f2bf(v.y), f2bf(v.z), f2bf(v.w));
        *(ushort4*)(qn2b + base) = u;
    }
}

// ---------------------------------------------------------------------------
// MFMA bf16 GEMM: C[M,N](fp32 or relu->bf16) = A_bf[M,K] @ W_bf[N,K]^T
// (+bias fp32)(+add fp32). 64x64 block tile, 4 waves, 16x16x32 mfma.
// ---------------------------------------------------------------------------
template <bool RELU_BF_OUT, bool HAS_ADD, bool HAS_BIAS>
__global__ __launch_bounds__(256) void mfma_gemm(
    const unsigned short* __restrict__ Abf, const unsigned short* __restrict__ Wbf,
    const float* __restrict__ bias, const float* __restrict__ add,
    float* __restrict__ Cf, unsigned short* __restrict__ Cbf,
    int N_, int K_)
{
    __shared__ short Asl[64][40];   // +8 pad: 2-way LDS conflicts only (free)
    __shared__ short Wsl[64][40];
    const int t = threadIdx.x;
    const int w = t >> 6, l = t & 63;
    const int l15 = l & 15, q = l >> 4;
    const int bm = blockIdx.y * 64, bn = blockIdx.x * 64;

    const int srow = t >> 2, skoff = (t & 3) * 8;
    const unsigned short* Ap = Abf + (size_t)(bm + srow) * K_ + skoff;
    const unsigned short* Wp = Wbf + (size_t)(bn + srow) * K_ + skoff;

    floatx4 acc[4];
    #pragma unroll
    for (int jf = 0; jf < 4; ++jf) acc[jf] = (floatx4){0.f, 0.f, 0.f, 0.f};

    for (int k0 = 0; k0 < K_; k0 += 32) {
        short8 av = *(const short8*)(Ap + k0);
        short8 wv = *(const short8*)(Wp + k0);
        __syncthreads();
        *(short8*)&Asl[srow][skoff] = av;
        *(short8*)&Wsl[srow][skoff] = wv;
        __syncthreads();
        short8 a = *(const short8*)&Asl[w * 16 + l15][q * 8];
        #pragma unroll
        for (int jf = 0; jf < 4; ++jf) {
            short8 b = *(const short8*)&Wsl[jf * 16 + l15][q * 8];
            acc[jf] = __builtin_amdgcn_mfma_f32_16x16x32_bf16(a, b, acc[jf], 0, 0, 0);
        }
    }

    #pragma unroll
    for (int jf = 0; jf < 4; ++jf) {
        const int col = bn + jf * 16 + l15;
        float bv = HAS_BIAS ? bias[col] : 0.f;
        #pragma unroll
        for (int r = 0; r < 4; ++r) {
            const int m = bm + w * 16 + q * 4 + r;
            float v = acc[jf][r] + bv;
            if (HAS_ADD) v += add[(size_t)m * N_ + col];
            if (RELU_BF_OUT) Cbf[(size_t)m * N_ + col] = f2bf(fmaxf(v, 0.f));
            else             Cf [(size_t)m * N_ + col] = v;
        }
    }
}

// ---------------------------------------------------------------------------
// LayerNorm per row (+ qg2_bf write); block 1024: support rows + mean + l2norm
// ---------------------------------------------------------------------------
__global__ __launch_bounds__(256) void ln_kernel(
    const float* __restrict__ y, const float* __restrict__ g,
    const float* __restrict__ beta, float* __restrict__ out,
    unsigned short* __restrict__ outb, float* __restrict__ sg0,
    float* __restrict__ sgn)
{
    __shared__ float rs[4], rq[4];
    const int t = threadIdx.x;
    const int lane = t & 63, wave = t >> 6;

    if (blockIdx.x < 1024) {
        const int row = blockIdx.x;
        float v = y[row * 256 + t];
        float s = v, q = v * v;
        #pragma unroll
        for (int i = 32; i >= 1; i >>= 1) { s += __shfl_xor(s, i, 64); q += __shfl_xor(q, i, 64); }
        if (lane == 0) { rs[wave] = s; rq[wave] = q; }
        __syncthreads();
        float tot  = rs[0] + rs[1] + rs[2] + rs[3];
        float totq = rq[0] + rq[1] + rq[2] + rq[3];
        float mu  = tot * (1.0f / 256.0f);
        float var = fmaxf(totq * (1.0f / 256.0f) - mu * mu, 0.0f);
        float o = g[t] * (v - mu) / sqrtf(var + 1e-5f) + beta[t];
        out[row * 256 + t]  = o;
        outb[row * 256 + t] = f2bf(o);
    } else {
        float acc = 0.f;
        for (int r = 0; r < FEW; ++r) {
            __syncthreads();
            float v = y[(BB + r) * 256 + t];
            float s = v, q = v * v;
            #pragma unroll
            for (int i = 32; i >= 1; i >>= 1) { s += __shfl_xor(s, i, 64); q += __shfl_xor(q, i, 64); }
            if (lane == 0) { rs[wave] = s; rq[wave] = q; }
            __syncthreads();
            float tot  = rs[0] + rs[1] + rs[2] + rs[3];
            float totq = rq[0] + rq[1] + rq[2] + rq[3];
            float mu  = tot * (1.0f / 256.0f);
            float var = fmaxf(totq * (1.0f / 256.0f) - mu * mu, 0.0f);
            acc += g[t] * (v - mu) / sqrtf(var + 1e-5f) + beta[t];
        }
        acc *= (1.0f / FEW);
        sg0[t] = acc;
        __syncthreads();
        float q = acc * acc;
        #pragma unroll
        for (int i = 32; i >= 1; i >>= 1) q += __shfl_xor(q, i, 64);
        if (lane == 0) rq[wave] = q;
        __syncthreads();
        float nrm = sqrtf(rq[0] + rq[1] + rq[2] + rq[3]);
        sgn[t] = acc / fmaxf(nrm, 1e-12f);
    }
}

// gates compact layout: [0:256)=i [256:512)=f [512:768)=g [768:1024)=o
__global__ __launch_bounds__(256) void lstm_step1_kernel(
    const float* __restrict__ gates, const float* __restrict__ qg,
    const float* __restrict__ sg0, float* __restrict__ c1,
    unsigned short* __restrict__ hrb)
{
    const int row = blockIdx.x, t = threadIdx.x;
    const float* gr = gates + row * 1024;
    float iv = gr[t], gv = gr[512 + t], ov = gr[768 + t];
    float cv = sigf(iv) * tanhf(gv);          // c0 = 0 => f-term drops
    c1[row * 256 + t] = cv;
    float hf = sigf(ov) * tanhf(cv);
    hrb[row * 512 + t]       = f2bf(qg[row * 256 + t] + hf);  // h1
    hrb[row * 512 + 256 + t] = f2bf(sg0[t]);                  // r (attn == 1)
}

__global__ __launch_bounds__(256) void lstm_step2_kernel(
    const float* __restrict__ gates, const float* __restrict__ c1,
    const float* __restrict__ qg, const float* __restrict__ sgn,
    float* __restrict__ outv)
{
    __shared__ float rn[4], rd[4];
    const int row = blockIdx.x, t = threadIdx.x;
    const int lane = t & 63, wave = t >> 6;
    const float* gr = gates + row * 1024;
    float iv = gr[t], fv = gr[256 + t], gv = gr[512 + t], ov = gr[768 + t];
    float cv = sigf(fv) * c1[row * 256 + t] + sigf(iv) * tanhf(gv);
    float h2 = qg[row * 256 + t] + sigf(ov) * tanhf(cv);
    float nn = h2 * h2, dd = h2 * sgn[t];
    #pragma unroll
    for (int i = 32; i >= 1; i >>= 1) { nn += __shfl_xor(nn, i, 64); dd += __shfl_xor(dd, i, 64); }
    if (lane == 0) { rn[wave] = nn; rd[wave] = dd; }
    __syncthreads();
    if (t == 0) {
        float n2 = rn[0] + rn[1] + rn[2] + rn[3];
        float dt = rd[0] + rd[1] + rd[2] + rd[3];
        outv[row] = dt / fmaxf(sqrtf(n2), 1e-12f);
    }
}

extern "C" void kernel_launch(void* const* d_in, const int* in_sizes, int n_in,
                              void* d_out, int out_size, void* d_ws, size_t ws_size,
                              hipStream_t stream)
{
    const int*   query    = (const int*)d_in[0];
    const int*   support  = (const int*)d_in[1];
    const int*   q_l_conn = (const int*)d_in[2];
    const int*   q_r_conn = (const int*)d_in[4];
    const int*   s_l_conn = (const int*)d_in[6];
    const int*   s_r_conn = (const int*)d_in[8];
    const float* emb      = (const float*)d_in[10];
    const float* gcn_W    = (const float*)d_in[11];
    const float* gcn_bias = (const float*)d_in[12];
    const float* gcn_b    = (const float*)d_in[13];
    const float* se_w1    = (const float*)d_in[14];
    const float* se_b1    = (const float*)d_in[15];
    const float* se_w2    = (const float*)d_in[16];
    const float* se_b2    = (const float*)d_in[17];
    const float* ln_g     = (const float*)d_in[18];
    const float* ln_b     = (const float*)d_in[19];
    const float* W_ih     = (const float*)d_in[20];
    const float* W_hh     = (const float*)d_in[21];
    const float* b_ih     = (const float*)d_in[22];
    const float* b_hh     = (const float*)d_in[23];
    float* out = (float*)d_out;

    float* ws     = (float*)d_ws;
    float* qn2    = ws;                    // 1088*256 f
    float* yq     = qn2    + 1088 * 256;   // 1088*256 f
    float* qg2    = yq     + 1088 * 256;   // 1088*256 f
    float* sg0    = qg2    + 1088 * 256;   // 256
    float* sgn    = sg0    + 256;          // 256
    float* gates  = sgn    + 256;          // 1024*1024 f
    float* c1     = gates  + 1024 * 1024;  // 1024*256 f
    float* avgbuf = c1     + 1024 * 256;   // 2112*256 f
    float* bias_c = avgbuf + 2112 * 256;   // 1024 f
    unsigned short* qn2b = (unsigned short*)(bias_c + 1024);  // 1088*256 sh
    unsigned short* h1b  = qn2b + 1088 * 256;                 // 1088*512 sh
    unsigned short* qg2b = h1b  + 1088 * 512;                 // 1024*256 sh
    unsigned short* hrb  = qg2b + 1024 * 256;                 // 1024*512 sh
    unsigned short* w1b  = hrb  + 1024 * 512;                 // 512*256 sh
    unsigned short* w2b  = w1b  + 512 * 256;                  // 256*512 sh
    unsigned short* wihb = w2b  + 256 * 512;                  // 1024*256 sh
    unsigned short* whhb = wihb + 1024 * 256;                 // 1024*512 sh

    // 1. front: per-row sims+rank+avg -> avgbuf  ||  weight convert
    front_kernel<<<NROW + 4100, 256, 0, stream>>>(
        query, support, q_l_conn, q_r_conn, s_l_conn, s_r_conn, emb, avgbuf,
        se_w1, se_w2, W_ih, W_hh, b_ih, b_hh, w1b, w2b, wihb, whhb, bias_c);

    // 2. GCN matvec GEMM -> qn2 (f32 + bf16)
    gcn_gemm_kernel<<<dim3(2, 33), 256, 0, stream>>>(
        avgbuf, gcn_W, gcn_bias, gcn_b, qn2, qn2b);

    // 3. SE GEMM1 (MFMA): h1_bf = bf16(relu(qn2 @ w1^T + b1))
    mfma_gemm<true, false, true><<<dim3(8, 17), 256, 0, stream>>>(
        qn2b, w1b, se_b1, nullptr, nullptr, h1b, 512, 256);

    // 4. SE GEMM2 (MFMA): yq = h1 @ w2^T + b2 + qn2
    mfma_gemm<false, true, true><<<dim3(4, 17), 256, 0, stream>>>(
        h1b, w2b, se_b2, qn2, yq, nullptr, 256, 512);

    // 5. LayerNorm -> qg2 (f32 + bf16) (+ support mean + l2norm in block 1024)
    ln_kernel<<<1025, 256, 0, stream>>>(yq, ln_g, ln_b, qg2, qg2b, sg0, sgn);

    // 6. gates = qg2 @ W_ih'^T + (b_ih+b_hh)  (MFMA, gate-compacted)
    mfma_gemm<false, false, true><<<dim3(16, 16), 256, 0, stream>>>(
        qg2b, wihb, bias_c, nullptr, gates, nullptr, 1024, 256);

    // 7. LSTM step 1 (c0=0, h_r0=0) -> c1, hr_bf
    lstm_step1_kernel<<<1024, 256, 0, stream>>>(gates, qg2, sg0, c1, hrb);

    // 8. gates += hr @ W_hh'^T  (MFMA, in-place add)
    mfma_gemm<false, true, false><<<dim3(16, 16), 256, 0, stream>>>(
        hrb, whhb, nullptr, gates, gates, nullptr, 1024, 512);

    // 9. LSTM step 2 + l2norm + dot(support_gn)
    lstm_step2_kernel<<<1024, 256, 0, stream>>>(gates, c1, qg2, sgn, out);
}